// Round 10
// baseline (184.902 us; speedup 1.0000x reference)
//
#include <hip/hip_runtime.h>

// ForwardKinematics fp32: rotations (B,24,4) wxyz + positions (B,24,3)
// -> global joint positions (B,24,3). Fixed SMPL tree.
//
// Round 14: fix r13b's cross-wave LDS race by moving the scatter to the
// other side of barrier B. TWO producer/consumer blocks per CU.
//  - r13b bug: store_chunk (overlay reads, addr F+F/72) and scatter_lds
//    (quat writes, addr f+4(f/96)) hit ldsR[q^1] with DIFFERENT pitch
//    transforms; round i of one wave's scatter overlaps round n=i of the
//    NEXT wave's store reads (e.g. scatter f=1264 -> dw 1316-1319 vs
//    store F=1296 -> dw 1314-1317). Intra-wave fence can't order
//    cross-wave DS ops -> corrupted outputs (absmax 13.4).
//  - Fix: Phase A: compute chains(buf q) || mem {issue loads, store
//    chunk c-G from overlay ldsR[q^1]}. Barrier. Phase B: compute emit
//    -> overlay ldsR[q] || mem scatter -> ldsR/ldsP[q^1]. Barrier.
//    Store-read(q^1) vs scatter-write(q^1) now barrier-separated;
//    emit(q) vs scatter(q^1) disjoint buffers. Full pairwise audit done
//    across gens i,i+1,i+2 + prologue/epilogue.
//  - Staged regs vr/vp (40 VGPR) live across barrier B on mem waves
//    only; branch-disjoint liveness keeps union under the (512,4)=128
//    cap (r8 spill lesson; verify via VGPR_Count/WRITE_SIZE).
//  - LDS 77.5 KB -> 2 blocks/CU = independent barrier domains (r12's
//    residual: gen 4.0us vs 1.5us path model = barrier serialization).
//  - SPB 56, persistent GRIDP=512, nontemporal full-line stores.

typedef float f32x4 __attribute__((ext_vector_type(4)));

struct M { float r0,r1,r2,r3,r4,r5,r6,r7,r8,tx,ty,tz; };

__device__ __forceinline__ M loc(float a, float b, float c, float d,
                                 float px, float py, float pz) {
    float inv = rsqrtf(a*a + b*b + c*c + d*d);
    float qw = a*inv, qx = b*inv, qy = c*inv, qz = d*inv;
    float x2 = qx+qx, y2 = qy+qy, z2 = qz+qz;
    float xx = qx*x2, yy = qy*y2, zz = qz*z2;
    float xy = qx*y2, yz = qy*z2, xz = qx*z2;
    float wx = qw*x2, wy = qw*y2, wz = qw*z2;
    M m;
    m.r0 = 1.f-(yy+zz); m.r1 = xy-wz;       m.r2 = xz+wy;
    m.r3 = xy+wz;       m.r4 = 1.f-(xx+zz); m.r5 = yz-wx;
    m.r6 = xz-wy;       m.r7 = yz+wx;       m.r8 = 1.f-(xx+yy);
    m.tx = px; m.ty = py; m.tz = pz;
    return m;
}

__device__ __forceinline__ M mul(const M& a, const M& b) {
    M c;
    c.r0 = a.r0*b.r0 + a.r1*b.r3 + a.r2*b.r6;
    c.r1 = a.r0*b.r1 + a.r1*b.r4 + a.r2*b.r7;
    c.r2 = a.r0*b.r2 + a.r1*b.r5 + a.r2*b.r8;
    c.r3 = a.r3*b.r0 + a.r4*b.r3 + a.r5*b.r6;
    c.r4 = a.r3*b.r1 + a.r4*b.r4 + a.r5*b.r7;
    c.r5 = a.r3*b.r2 + a.r4*b.r5 + a.r5*b.r8;
    c.r6 = a.r6*b.r0 + a.r7*b.r3 + a.r8*b.r6;
    c.r7 = a.r6*b.r1 + a.r7*b.r4 + a.r8*b.r7;
    c.r8 = a.r6*b.r2 + a.r7*b.r5 + a.r8*b.r8;
    c.tx = a.r0*b.tx + a.r1*b.ty + a.r2*b.tz + a.tx;
    c.ty = a.r3*b.tx + a.r4*b.ty + a.r5*b.tz + a.ty;
    c.tz = a.r6*b.tx + a.r7*b.ty + a.r8*b.tz + a.tz;
    return c;
}

#define SPB    56
#define NTHR   512
#define GRIDP  512   // persistent: 2 blocks per CU
#define RPITCH 100   // 16B-aligned quat rows -> ds_read_b128
#define PPITCH 73    // odd -> conflict-free b32 access
#define OPITCH 73    // output overlay pitch (inside ldsR region)

// Wave-uniform 4-way tree split (verified rounds 7-12). MT = matrices
// computed (topological), PR = parent index into MT (-1 = root), writes
// are the suffix from WS. Each of 24 joints written exactly once.
constexpr int MT0[6]  = {0,1,2,4,7,10};
constexpr int PR0[6]  = {-1,0,0,1,3,4};
constexpr int MT1[8]  = {0,2,5,8,11,3,6,9};
constexpr int PR1[8]  = {-1,0,1,2,3,0,5,6};
constexpr int MT2[11] = {0,3,6,9,12,15,13,16,18,20,22};
constexpr int PR2[11] = {-1,0,1,2,3,4,3,6,7,8,9};
constexpr int MT3[9]  = {0,3,6,9,14,17,19,21,23};
constexpr int PR3[9]  = {-1,0,1,2,3,4,5,6,7};

// Chains; outputs (suffix k>=WS) go to regs ob[3*(k-WS)+e]. Max 7 joints.
template<int NM>
__device__ __forceinline__ void run_chain(const int (&MT)[NM], const int (&PR)[NM],
                                          int WS,
                                          const float* __restrict__ R,
                                          const float* __restrict__ P,
                                          float* __restrict__ ob) {
    M G[NM];
    {
        f32x4 q = *(const f32x4*)(R);
        G[0] = loc(q.x, q.y, q.z, q.w, P[0], P[1], P[2]);
    }
    if (WS == 0) { ob[0]=G[0].tx; ob[1]=G[0].ty; ob[2]=G[0].tz; }
#pragma unroll
    for (int k = 1; k < NM; ++k) {
        const int j = MT[k];
        f32x4 q = *(const f32x4*)(R + 4*j);
        M L = loc(q.x, q.y, q.z, q.w, P[3*j], P[3*j+1], P[3*j+2]);
        G[k] = mul(G[PR[k]], L);
        if (k >= WS) {
            const int o = 3*(k-WS);
            ob[o+0]=G[k].tx; ob[o+1]=G[k].ty; ob[o+2]=G[k].tz;
        }
    }
}

template<int NM>
__device__ __forceinline__ void emit_out(const int (&MT)[NM], int WS,
                                         const float* __restrict__ ob,
                                         float* __restrict__ ovl) {
#pragma unroll
    for (int k = 0; k < NM; ++k) {
        if (k >= WS) {
            const int j = MT[k], o = 3*(k-WS);
            ovl[3*j+0]=ob[o+0]; ovl[3*j+1]=ob[o+1]; ovl[3*j+2]=ob[o+2];
        }
    }
}

// ---- memory-wave helpers (mt in [0,256)) ----
// rot: 56*96=5376 dw = 1344 x4 slots = 5*256 + 64
// pos: 56*72=4032 dw = 1008 x4 slots = 3*256 + 240
__device__ __forceinline__ void load_regs(int c, int mt,
                                          const float* __restrict__ rot,
                                          const float* __restrict__ pos,
                                          size_t limR, size_t limP,
                                          f32x4 (&vr)[6], f32x4 (&vp)[4]) {
    const size_t baseR = (size_t)c * (SPB*96);
    const size_t baseP = (size_t)c * (SPB*72);
#pragma unroll
    for (int i = 0; i < 6; ++i) {
        const bool g = (i < 5) || (mt < 64);
        const size_t gi = baseR + (size_t)(i*1024 + 4*mt);
        f32x4 v = {0.f,0.f,0.f,0.f};
        if (g && gi < limR) v = *(const f32x4*)(rot + gi);
        vr[i] = v;
    }
#pragma unroll
    for (int i = 0; i < 4; ++i) {
        const bool g = (i < 3) || (mt < 240);
        const size_t gi = baseP + (size_t)(i*1024 + 4*mt);
        f32x4 v = {0.f,0.f,0.f,0.f};
        if (g && gi < limP) v = *(const f32x4*)(pos + gi);
        vp[i] = v;
    }
}

__device__ __forceinline__ void scatter_lds(int mt,
                                            float* Rb,
                                            float* Pb,
                                            const f32x4 (&vr)[6],
                                            const f32x4 (&vp)[4]) {
#pragma unroll
    for (int i = 0; i < 6; ++i) {
        if ((i < 5) || (mt < 64)) {
            const int f = i*1024 + 4*mt;
            const int s = f / 96, r = f - 96*s;
            *(f32x4*)(Rb + s*RPITCH + r) = vr[i];    // aligned b128 write
        }
    }
#pragma unroll
    for (int i = 0; i < 4; ++i) {
        if ((i < 3) || (mt < 240)) {
            const int f = i*1024 + 4*mt;
            const int s = f / 72, r = f - 72*s;
            float* d = Pb + s*PPITCH + r;
            d[0]=vp[i].x; d[1]=vp[i].y; d[2]=vp[i].z; d[3]=vp[i].w;
        }
    }
}

__device__ __forceinline__ void store_chunk(const float* Ov,
                                            int c, int mt, size_t limP,
                                            float* __restrict__ out) {
    const size_t baseO = (size_t)c * (SPB*72);
#pragma unroll
    for (int n = 0; n < 4; ++n) {
        if ((n < 3) || (mt < 240)) {
            const int F = n*1024 + 4*mt;
            const int s = F / 72, r = F - 72*s;
            const size_t gi = baseO + (size_t)F;
            if (gi < limP) {
                f32x4 v = { Ov[s*OPITCH+r+0], Ov[s*OPITCH+r+1],
                            Ov[s*OPITCH+r+2], Ov[s*OPITCH+r+3] };
                __builtin_nontemporal_store(v, (f32x4*)(out + gi));
            }
        }
    }
}

__global__ __launch_bounds__(NTHR, 4) void fk_kernel(
    const float* __restrict__ rot,   // B*96 floats (quat wxyz per joint)
    const float* __restrict__ pos,   // B*72 floats
    float*       __restrict__ out,   // B*72 floats
    int B)
{
    // quats (pitch 100); after compute, outputs overlay same region at
    // pitch 73 (56*73=4088 dw < 5600 dw). pos pitch 73.
    __shared__ __align__(16) float ldsR[2][SPB * RPITCH];  // 2 x 22400 B
    __shared__ float ldsP[2][SPB * PPITCH];                // 2 x 16352 B
                                                           // total 77504 B

    const int t   = threadIdx.x;
    const int w   = t >> 6;
    const bool cw = (w < 4);          // compute waves 0..3, mem waves 4..7
    const int mt  = t & 255;
    const int nch = (B + SPB - 1) / SPB;
    const size_t limR = (size_t)B * 96;
    const size_t limP = (size_t)B * 72;

    // ---- prologue: mem waves stage chunk c0 into buffer 0 ----
    const int c0 = blockIdx.x;
    {
        f32x4 vr[6]; f32x4 vp[4];
        if (!cw && c0 < nch) {
            load_regs(c0, mt, rot, pos, limR, limP, vr, vp);
            scatter_lds(mt, ldsR[0], ldsP[0], vr, vp);
        }
    }
    __syncthreads();

    int i = 0, c = c0;
    float ob[21];
    f32x4 vr[6]; f32x4 vp[4];        // staged regs, live across barrier B
    for (; c < nch; c += GRIDP, ++i) {
        const int q = i & 1;
        const int l = t & 63;
        const bool ldv = (c + GRIDP) < nch;

        // ================= PHASE A =================
        if (cw) {
            // chains on buffer q -> ob regs
            const int b = c * SPB + l;
            if ((l < SPB) && (b < B)) {
                const float* R = &ldsR[q][l * RPITCH];
                const float* P = &ldsP[q][l * PPITCH];
                switch (w) {
                    case 0:  run_chain(MT0, PR0, 0, R, P, ob); break;
                    case 1:  run_chain(MT1, PR1, 2, R, P, ob); break;
                    case 2:  run_chain(MT2, PR2, 4, R, P, ob); break;
                    default: run_chain(MT3, PR3, 4, R, P, ob); break;
                }
            }
        } else {
            // issue next chunk's loads (fly across store+barrier+compute)
            if (ldv) load_regs(c + GRIDP, mt, rot, pos, limR, limP, vr, vp);
            // store chunk c-GRIDP from overlay of ldsR[q^1]
            if (i > 0) store_chunk(&ldsR[q^1][0], c - GRIDP, mt, limP, out);
        }
        __syncthreads();   // barrier B: quat reads of buf q done; overlay
                           // reads of buf q^1 done (ALL waves)

        // ================= PHASE B =================
        if (cw) {
            // emit outputs -> overlay of ldsR[q] (quats of q now dead)
            const int b = c * SPB + l;
            if ((l < SPB) && (b < B)) {
                float* ovl = &ldsR[q][l * OPITCH];
                switch (w) {
                    case 0:  emit_out(MT0, 0, ob, ovl); break;
                    case 1:  emit_out(MT1, 2, ob, ovl); break;
                    case 2:  emit_out(MT2, 4, ob, ovl); break;
                    default: emit_out(MT3, 4, ob, ovl); break;
                }
            }
        } else {
            // scatter new chunk into buffers q^1 (store reads done at B)
            if (ldv) scatter_lds(mt, ldsR[q^1], ldsP[q^1], vr, vp);
        }
        __syncthreads();   // gen end: overlay(q) + buffers(q^1) ready
    }

    // ---- epilogue: store final chunk's outputs ----
    if (!cw && i > 0)
        store_chunk(&ldsR[(i-1) & 1][0], c - GRIDP, mt, limP, out);
}

extern "C" void kernel_launch(void* const* d_in, const int* in_sizes, int n_in,
                              void* d_out, int out_size, void* d_ws, size_t ws_size,
                              hipStream_t stream) {
    const int B = out_size / 72;           // (B,24,3)
    const void* rot = nullptr;
    const void* pos = nullptr;
    for (int i = 0; i < n_in; ++i) {       // resolve by size, not order
        if      (in_sizes[i] == B * 96) rot = d_in[i];
        else if (in_sizes[i] == B * 72) pos = d_in[i];
    }
    if (!rot) rot = d_in[2];
    if (!pos) pos = d_in[1];

    const int nch  = (B + SPB - 1) / SPB;  // 2341 chunks @ B=131072
    const int grid = (nch < GRIDP) ? nch : GRIDP;
    fk_kernel<<<grid, NTHR, 0, stream>>>(
        (const float*)rot, (const float*)pos, (float*)d_out, B);
}

// Round 11
// 137.143 us; speedup vs baseline: 1.3482x; 1.3482x over previous
//
#include <hip/hip_runtime.h>

// ForwardKinematics fp32: rotations (B,24,4) wxyz + positions (B,24,3)
// -> global joint positions (B,24,3). Fixed SMPL tree.
//
// Round 15: r14 with the launch-bounds spill fixed.
//  - r14 evidence: (256,3)->cap170, (512,6)->40, (512,4)->64 all fit
//    cap = 2048/(arg2 * waves_per_block): this compiler treats arg2 as
//    MIN BLOCKS PER CU against the 2048-VGPR/CU pool. (512,4) therefore
//    capped at 64 VGPR -> ~100-reg live set spilled -> FETCH+WRITE
//    inflated 94->287 MB, fk 90us. Structure itself passed correctness.
//  - Fix: (512,2) -> cap 128, natural ~95-110 -> no spill. LDS 77.5 KB
//    and VGPR 128 both admit exactly 2 blocks/CU = 2 independent
//    barrier domains (the r13/r14 hypothesis, now fairly tested).
//  - Schedule (race-audited in r14, passed): Phase A: compute chains
//    (buf q) || mem {issue loads c+G, store chunk c-G from overlay of
//    ldsR[q^1]}. Barrier B. Phase B: compute emit -> overlay ldsR[q] ||
//    mem scatter -> ldsR/ldsP[q^1]. Barrier. Store-read(q^1) vs
//    scatter-write(q^1) barrier-separated; emit(q) vs scatter(q^1)
//    disjoint.
//  - SPB 56, persistent GRIDP=512, nontemporal full-line stores.

typedef float f32x4 __attribute__((ext_vector_type(4)));

struct M { float r0,r1,r2,r3,r4,r5,r6,r7,r8,tx,ty,tz; };

__device__ __forceinline__ M loc(float a, float b, float c, float d,
                                 float px, float py, float pz) {
    float inv = rsqrtf(a*a + b*b + c*c + d*d);
    float qw = a*inv, qx = b*inv, qy = c*inv, qz = d*inv;
    float x2 = qx+qx, y2 = qy+qy, z2 = qz+qz;
    float xx = qx*x2, yy = qy*y2, zz = qz*z2;
    float xy = qx*y2, yz = qy*z2, xz = qx*z2;
    float wx = qw*x2, wy = qw*y2, wz = qw*z2;
    M m;
    m.r0 = 1.f-(yy+zz); m.r1 = xy-wz;       m.r2 = xz+wy;
    m.r3 = xy+wz;       m.r4 = 1.f-(xx+zz); m.r5 = yz-wx;
    m.r6 = xz-wy;       m.r7 = yz+wx;       m.r8 = 1.f-(xx+yy);
    m.tx = px; m.ty = py; m.tz = pz;
    return m;
}

__device__ __forceinline__ M mul(const M& a, const M& b) {
    M c;
    c.r0 = a.r0*b.r0 + a.r1*b.r3 + a.r2*b.r6;
    c.r1 = a.r0*b.r1 + a.r1*b.r4 + a.r2*b.r7;
    c.r2 = a.r0*b.r2 + a.r1*b.r5 + a.r2*b.r8;
    c.r3 = a.r3*b.r0 + a.r4*b.r3 + a.r5*b.r6;
    c.r4 = a.r3*b.r1 + a.r4*b.r4 + a.r5*b.r7;
    c.r5 = a.r3*b.r2 + a.r4*b.r5 + a.r5*b.r8;
    c.r6 = a.r6*b.r0 + a.r7*b.r3 + a.r8*b.r6;
    c.r7 = a.r6*b.r1 + a.r7*b.r4 + a.r8*b.r7;
    c.r8 = a.r6*b.r2 + a.r7*b.r5 + a.r8*b.r8;
    c.tx = a.r0*b.tx + a.r1*b.ty + a.r2*b.tz + a.tx;
    c.ty = a.r3*b.tx + a.r4*b.ty + a.r5*b.tz + a.ty;
    c.tz = a.r6*b.tx + a.r7*b.ty + a.r8*b.tz + a.tz;
    return c;
}

#define SPB    56
#define NTHR   512
#define GRIDP  512   // persistent: 2 blocks per CU
#define RPITCH 100   // 16B-aligned quat rows -> ds_read_b128
#define PPITCH 73    // odd -> conflict-free b32 access
#define OPITCH 73    // output overlay pitch (inside ldsR region)

// Wave-uniform 4-way tree split (verified rounds 7-12). MT = matrices
// computed (topological), PR = parent index into MT (-1 = root), writes
// are the suffix from WS. Each of 24 joints written exactly once.
constexpr int MT0[6]  = {0,1,2,4,7,10};
constexpr int PR0[6]  = {-1,0,0,1,3,4};
constexpr int MT1[8]  = {0,2,5,8,11,3,6,9};
constexpr int PR1[8]  = {-1,0,1,2,3,0,5,6};
constexpr int MT2[11] = {0,3,6,9,12,15,13,16,18,20,22};
constexpr int PR2[11] = {-1,0,1,2,3,4,3,6,7,8,9};
constexpr int MT3[9]  = {0,3,6,9,14,17,19,21,23};
constexpr int PR3[9]  = {-1,0,1,2,3,4,5,6,7};

// Chains; outputs (suffix k>=WS) go to regs ob[3*(k-WS)+e]. Max 7 joints.
template<int NM>
__device__ __forceinline__ void run_chain(const int (&MT)[NM], const int (&PR)[NM],
                                          int WS,
                                          const float* __restrict__ R,
                                          const float* __restrict__ P,
                                          float* __restrict__ ob) {
    M G[NM];
    {
        f32x4 q = *(const f32x4*)(R);
        G[0] = loc(q.x, q.y, q.z, q.w, P[0], P[1], P[2]);
    }
    if (WS == 0) { ob[0]=G[0].tx; ob[1]=G[0].ty; ob[2]=G[0].tz; }
#pragma unroll
    for (int k = 1; k < NM; ++k) {
        const int j = MT[k];
        f32x4 q = *(const f32x4*)(R + 4*j);
        M L = loc(q.x, q.y, q.z, q.w, P[3*j], P[3*j+1], P[3*j+2]);
        G[k] = mul(G[PR[k]], L);
        if (k >= WS) {
            const int o = 3*(k-WS);
            ob[o+0]=G[k].tx; ob[o+1]=G[k].ty; ob[o+2]=G[k].tz;
        }
    }
}

template<int NM>
__device__ __forceinline__ void emit_out(const int (&MT)[NM], int WS,
                                         const float* __restrict__ ob,
                                         float* __restrict__ ovl) {
#pragma unroll
    for (int k = 0; k < NM; ++k) {
        if (k >= WS) {
            const int j = MT[k], o = 3*(k-WS);
            ovl[3*j+0]=ob[o+0]; ovl[3*j+1]=ob[o+1]; ovl[3*j+2]=ob[o+2];
        }
    }
}

// ---- memory-wave helpers (mt in [0,256)) ----
// rot: 56*96=5376 dw = 1344 x4 slots = 5*256 + 64
// pos: 56*72=4032 dw = 1008 x4 slots = 3*256 + 240
__device__ __forceinline__ void load_regs(int c, int mt,
                                          const float* __restrict__ rot,
                                          const float* __restrict__ pos,
                                          size_t limR, size_t limP,
                                          f32x4 (&vr)[6], f32x4 (&vp)[4]) {
    const size_t baseR = (size_t)c * (SPB*96);
    const size_t baseP = (size_t)c * (SPB*72);
#pragma unroll
    for (int i = 0; i < 6; ++i) {
        const bool g = (i < 5) || (mt < 64);
        const size_t gi = baseR + (size_t)(i*1024 + 4*mt);
        f32x4 v = {0.f,0.f,0.f,0.f};
        if (g && gi < limR) v = *(const f32x4*)(rot + gi);
        vr[i] = v;
    }
#pragma unroll
    for (int i = 0; i < 4; ++i) {
        const bool g = (i < 3) || (mt < 240);
        const size_t gi = baseP + (size_t)(i*1024 + 4*mt);
        f32x4 v = {0.f,0.f,0.f,0.f};
        if (g && gi < limP) v = *(const f32x4*)(pos + gi);
        vp[i] = v;
    }
}

__device__ __forceinline__ void scatter_lds(int mt,
                                            float* Rb,
                                            float* Pb,
                                            const f32x4 (&vr)[6],
                                            const f32x4 (&vp)[4]) {
#pragma unroll
    for (int i = 0; i < 6; ++i) {
        if ((i < 5) || (mt < 64)) {
            const int f = i*1024 + 4*mt;
            const int s = f / 96, r = f - 96*s;
            *(f32x4*)(Rb + s*RPITCH + r) = vr[i];    // aligned b128 write
        }
    }
#pragma unroll
    for (int i = 0; i < 4; ++i) {
        if ((i < 3) || (mt < 240)) {
            const int f = i*1024 + 4*mt;
            const int s = f / 72, r = f - 72*s;
            float* d = Pb + s*PPITCH + r;
            d[0]=vp[i].x; d[1]=vp[i].y; d[2]=vp[i].z; d[3]=vp[i].w;
        }
    }
}

__device__ __forceinline__ void store_chunk(const float* Ov,
                                            int c, int mt, size_t limP,
                                            float* __restrict__ out) {
    const size_t baseO = (size_t)c * (SPB*72);
#pragma unroll
    for (int n = 0; n < 4; ++n) {
        if ((n < 3) || (mt < 240)) {
            const int F = n*1024 + 4*mt;
            const int s = F / 72, r = F - 72*s;
            const size_t gi = baseO + (size_t)F;
            if (gi < limP) {
                f32x4 v = { Ov[s*OPITCH+r+0], Ov[s*OPITCH+r+1],
                            Ov[s*OPITCH+r+2], Ov[s*OPITCH+r+3] };
                __builtin_nontemporal_store(v, (f32x4*)(out + gi));
            }
        }
    }
}

__global__ __launch_bounds__(NTHR, 2) void fk_kernel(
    const float* __restrict__ rot,   // B*96 floats (quat wxyz per joint)
    const float* __restrict__ pos,   // B*72 floats
    float*       __restrict__ out,   // B*72 floats
    int B)
{
    // quats (pitch 100); after compute, outputs overlay same region at
    // pitch 73 (56*73=4088 dw < 5600 dw). pos pitch 73.
    __shared__ __align__(16) float ldsR[2][SPB * RPITCH];  // 2 x 22400 B
    __shared__ float ldsP[2][SPB * PPITCH];                // 2 x 16352 B
                                                           // total 77504 B

    const int t   = threadIdx.x;
    const int w   = t >> 6;
    const bool cw = (w < 4);          // compute waves 0..3, mem waves 4..7
    const int mt  = t & 255;
    const int nch = (B + SPB - 1) / SPB;
    const size_t limR = (size_t)B * 96;
    const size_t limP = (size_t)B * 72;

    // ---- prologue: mem waves stage chunk c0 into buffer 0 ----
    const int c0 = blockIdx.x;
    {
        f32x4 vr[6]; f32x4 vp[4];
        if (!cw && c0 < nch) {
            load_regs(c0, mt, rot, pos, limR, limP, vr, vp);
            scatter_lds(mt, ldsR[0], ldsP[0], vr, vp);
        }
    }
    __syncthreads();

    int i = 0, c = c0;
    float ob[21];
    f32x4 vr[6]; f32x4 vp[4];        // staged regs, live across barrier B
    for (; c < nch; c += GRIDP, ++i) {
        const int q = i & 1;
        const int l = t & 63;
        const bool ldv = (c + GRIDP) < nch;

        // ================= PHASE A =================
        if (cw) {
            // chains on buffer q -> ob regs
            const int b = c * SPB + l;
            if ((l < SPB) && (b < B)) {
                const float* R = &ldsR[q][l * RPITCH];
                const float* P = &ldsP[q][l * PPITCH];
                switch (w) {
                    case 0:  run_chain(MT0, PR0, 0, R, P, ob); break;
                    case 1:  run_chain(MT1, PR1, 2, R, P, ob); break;
                    case 2:  run_chain(MT2, PR2, 4, R, P, ob); break;
                    default: run_chain(MT3, PR3, 4, R, P, ob); break;
                }
            }
        } else {
            // issue next chunk's loads (fly across store+barrier+compute)
            if (ldv) load_regs(c + GRIDP, mt, rot, pos, limR, limP, vr, vp);
            // store chunk c-GRIDP from overlay of ldsR[q^1]
            if (i > 0) store_chunk(&ldsR[q^1][0], c - GRIDP, mt, limP, out);
        }
        __syncthreads();   // barrier B: quat reads of buf q done; overlay
                           // reads of buf q^1 done (ALL waves)

        // ================= PHASE B =================
        if (cw) {
            // emit outputs -> overlay of ldsR[q] (quats of q now dead)
            const int b = c * SPB + l;
            if ((l < SPB) && (b < B)) {
                float* ovl = &ldsR[q][l * OPITCH];
                switch (w) {
                    case 0:  emit_out(MT0, 0, ob, ovl); break;
                    case 1:  emit_out(MT1, 2, ob, ovl); break;
                    case 2:  emit_out(MT2, 4, ob, ovl); break;
                    default: emit_out(MT3, 4, ob, ovl); break;
                }
            }
        } else {
            // scatter new chunk into buffers q^1 (store reads done at B)
            if (ldv) scatter_lds(mt, ldsR[q^1], ldsP[q^1], vr, vp);
        }
        __syncthreads();   // gen end: overlay(q) + buffers(q^1) ready
    }

    // ---- epilogue: store final chunk's outputs ----
    if (!cw && i > 0)
        store_chunk(&ldsR[(i-1) & 1][0], c - GRIDP, mt, limP, out);
}

extern "C" void kernel_launch(void* const* d_in, const int* in_sizes, int n_in,
                              void* d_out, int out_size, void* d_ws, size_t ws_size,
                              hipStream_t stream) {
    const int B = out_size / 72;           // (B,24,3)
    const void* rot = nullptr;
    const void* pos = nullptr;
    for (int i = 0; i < n_in; ++i) {       // resolve by size, not order
        if      (in_sizes[i] == B * 96) rot = d_in[i];
        else if (in_sizes[i] == B * 72) pos = d_in[i];
    }
    if (!rot) rot = d_in[2];
    if (!pos) pos = d_in[1];

    const int nch  = (B + SPB - 1) / SPB;  // 2341 chunks @ B=131072
    const int grid = (nch < GRIDP) ? nch : GRIDP;
    fk_kernel<<<grid, NTHR, 0, stream>>>(
        (const float*)rot, (const float*)pos, (float*)d_out, B);
}

// Round 12
// 125.420 us; speedup vs baseline: 1.4743x; 1.0935x over previous
//
#include <hip/hip_runtime.h>

// ForwardKinematics fp32: rotations (B,24,4) wxyz + positions (B,24,3)
// -> global joint positions (B,24,3). Fixed SMPL tree.
//
// Round 16: r12 (best proven: 123.95us total, fk ~32us) + ONE change:
//   nontemporal stores -> plain cached stores.
//   Mechanism: compiler emits s_waitcnt vmcnt(0) before EVERY s_barrier
//   (stores count in vmcnt). NT stores ack from the HBM write path
//   (~600-1000cy under load); cached stores ack at L2 (~100-200cy) with
//   identical eventual HBM traffic (full-line coverage -> clean
//   write-back, no RFO). r12/r15 paid ~4-5us per barrier epoch with NT;
//   r7/r9 (plain stores, no per-gen barrier drain) were never this
//   stall-bound. Single-variable A/B vs r12.
//
// Producer/consumer wave specialization (r12, verified):
//  - 512 thr = 4 compute waves + 4 memory waves. Persistent grid 256
//    (1 block/CU), 8 chunks of SPB=64 per block, double-buffered LDS.
//  - Per generation (ONE barrier): compute waves: chains on buf q ->
//    ldsO[q]. Mem waves: issue loads chunk c+1; store chunk c-1 from
//    ldsO[q^1] (load latency hides under store); scatter into buf q^1.
//    Race-free: store reads ldsO[q^1]; scatter writes ldsR/ldsP[q^1] --
//    DISJOINT arrays (r13's overlay-aliasing bug does not exist here).
//  - LDS 123 KB static (2x R/P/O) -> 1 block/CU, 8 waves.
//  - (512,2): 256-VGPR cap, live ~90 -> no spill (r8/r14 lesson:
//    arg2 is min BLOCKS/CU vs the 2048-VGPR pool on this compiler).
//  - 4-way wave-uniform DAG split unchanged (verified r7..r15).

typedef float f32x4 __attribute__((ext_vector_type(4)));

struct M { float r0,r1,r2,r3,r4,r5,r6,r7,r8,tx,ty,tz; };

__device__ __forceinline__ M loc(float a, float b, float c, float d,
                                 float px, float py, float pz) {
    float inv = rsqrtf(a*a + b*b + c*c + d*d);
    float qw = a*inv, qx = b*inv, qy = c*inv, qz = d*inv;
    float x2 = qx+qx, y2 = qy+qy, z2 = qz+qz;
    float xx = qx*x2, yy = qy*y2, zz = qz*z2;
    float xy = qx*y2, yz = qy*z2, xz = qx*z2;
    float wx = qw*x2, wy = qw*y2, wz = qw*z2;
    M m;
    m.r0 = 1.f-(yy+zz); m.r1 = xy-wz;       m.r2 = xz+wy;
    m.r3 = xy+wz;       m.r4 = 1.f-(xx+zz); m.r5 = yz-wx;
    m.r6 = xz-wy;       m.r7 = yz+wx;       m.r8 = 1.f-(xx+yy);
    m.tx = px; m.ty = py; m.tz = pz;
    return m;
}

__device__ __forceinline__ M mul(const M& a, const M& b) {
    M c;
    c.r0 = a.r0*b.r0 + a.r1*b.r3 + a.r2*b.r6;
    c.r1 = a.r0*b.r1 + a.r1*b.r4 + a.r2*b.r7;
    c.r2 = a.r0*b.r2 + a.r1*b.r5 + a.r2*b.r8;
    c.r3 = a.r3*b.r0 + a.r4*b.r3 + a.r5*b.r6;
    c.r4 = a.r3*b.r1 + a.r4*b.r4 + a.r5*b.r7;
    c.r5 = a.r3*b.r2 + a.r4*b.r5 + a.r5*b.r8;
    c.r6 = a.r6*b.r0 + a.r7*b.r3 + a.r8*b.r6;
    c.r7 = a.r6*b.r1 + a.r7*b.r4 + a.r8*b.r7;
    c.r8 = a.r6*b.r2 + a.r7*b.r5 + a.r8*b.r8;
    c.tx = a.r0*b.tx + a.r1*b.ty + a.r2*b.tz + a.tx;
    c.ty = a.r3*b.tx + a.r4*b.ty + a.r5*b.tz + a.ty;
    c.tz = a.r6*b.tx + a.r7*b.ty + a.r8*b.tz + a.tz;
    return c;
}

#define SPB    64
#define NTHR   512
#define GRIDP  256   // persistent blocks: 1 per CU
#define RPITCH 100   // 16B-aligned quat rows -> ds_read_b128
#define PPITCH 73    // odd -> conflict-free b32 access

// Wave-uniform 4-way tree split (verified rounds 7-15). MT = matrices
// computed (topological), PR = parent index into MT (-1 = root), writes
// are the suffix from WS. Each of 24 joints written exactly once.
constexpr int MT0[6]  = {0,1,2,4,7,10};
constexpr int PR0[6]  = {-1,0,0,1,3,4};
constexpr int MT1[8]  = {0,2,5,8,11,3,6,9};
constexpr int PR1[8]  = {-1,0,1,2,3,0,5,6};
constexpr int MT2[11] = {0,3,6,9,12,15,13,16,18,20,22};
constexpr int PR2[11] = {-1,0,1,2,3,4,3,6,7,8,9};
constexpr int MT3[9]  = {0,3,6,9,14,17,19,21,23};
constexpr int PR3[9]  = {-1,0,1,2,3,4,5,6,7};

template<int NM>
__device__ __forceinline__ void run_chain(const int (&MT)[NM], const int (&PR)[NM],
                                          int WS,
                                          const float* __restrict__ R,
                                          const float* __restrict__ P,
                                          float* __restrict__ O) {
    M G[NM];
    {
        f32x4 q = *(const f32x4*)(R);
        G[0] = loc(q.x, q.y, q.z, q.w, P[0], P[1], P[2]);
    }
    if (WS == 0) { O[0]=G[0].tx; O[1]=G[0].ty; O[2]=G[0].tz; }
#pragma unroll
    for (int k = 1; k < NM; ++k) {
        const int j = MT[k];
        f32x4 q = *(const f32x4*)(R + 4*j);
        M L = loc(q.x, q.y, q.z, q.w, P[3*j], P[3*j+1], P[3*j+2]);
        G[k] = mul(G[PR[k]], L);
        if (k >= WS) { O[3*j]=G[k].tx; O[3*j+1]=G[k].ty; O[3*j+2]=G[k].tz; }
    }
}

// ---- memory-wave helpers (mt in [0,256)) ----
__device__ __forceinline__ void load_regs(int c, int mt,
                                          const float* __restrict__ rot,
                                          const float* __restrict__ pos,
                                          size_t limR, size_t limP,
                                          f32x4 (&vr)[6], f32x4 (&vp)[5]) {
    const size_t baseR = (size_t)c * (SPB*96);   // 6144 dw/chunk
    const size_t baseP = (size_t)c * (SPB*72);   // 4608 dw/chunk
#pragma unroll
    for (int i = 0; i < 6; ++i) {
        const size_t gi = baseR + (size_t)(i*1024 + 4*mt);
        f32x4 v = {0.f,0.f,0.f,0.f};
        if (gi < limR) v = *(const f32x4*)(rot + gi);
        vr[i] = v;
    }
#pragma unroll
    for (int i = 0; i < 5; ++i) {
        const bool g = (i < 4) || (mt < 128);
        const size_t gi = baseP + (size_t)(i*1024 + 4*mt);
        f32x4 v = {0.f,0.f,0.f,0.f};
        if (g && gi < limP) v = *(const f32x4*)(pos + gi);
        vp[i] = v;
    }
}

__device__ __forceinline__ void scatter_lds(int mt,
                                            float* __restrict__ Rb,
                                            float* __restrict__ Pb,
                                            const f32x4 (&vr)[6],
                                            const f32x4 (&vp)[5]) {
#pragma unroll
    for (int i = 0; i < 6; ++i) {
        const int f = i*1024 + 4*mt;
        const int s = f / 96, r = f - 96*s;
        *(f32x4*)(Rb + s*RPITCH + r) = vr[i];     // aligned b128 write
    }
#pragma unroll
    for (int i = 0; i < 5; ++i) {
        if ((i < 4) || (mt < 128)) {
            const int f = i*1024 + 4*mt;
            const int s = f / 72, r = f - 72*s;
            float* d = Pb + s*PPITCH + r;
            d[0]=vp[i].x; d[1]=vp[i].y; d[2]=vp[i].z; d[3]=vp[i].w;
        }
    }
}

__device__ __forceinline__ void store_chunk(const float* __restrict__ Ob,
                                            int c, int mt, size_t limP,
                                            float* __restrict__ out) {
    const size_t baseO = (size_t)c * (SPB*72);
#pragma unroll
    for (int n = 0; n < 5; ++n) {
        if ((n < 4) || (mt < 128)) {
            const int F = n*1024 + 4*mt;
            const int s = F / 72, r = F - 72*s;
            const size_t gi = baseO + (size_t)F;
            if (gi < limP) {
                f32x4 v = { Ob[s*PPITCH+r+0], Ob[s*PPITCH+r+1],
                            Ob[s*PPITCH+r+2], Ob[s*PPITCH+r+3] };
                *(f32x4*)(out + gi) = v;   // cached store: acks at L2,
                                           // full-line coverage -> no RFO
            }
        }
    }
}

__global__ __launch_bounds__(NTHR, 2) void fk_kernel(
    const float* __restrict__ rot,   // B*96 floats (quat wxyz per joint)
    const float* __restrict__ pos,   // B*72 floats
    float*       __restrict__ out,   // B*72 floats
    int B)
{
    __shared__ __align__(16) float ldsR[2][SPB * RPITCH];  // 2 x 25600 B
    __shared__ float ldsP[2][SPB * PPITCH];                // 2 x 18688 B
    __shared__ float ldsO[2][SPB * PPITCH];                // 2 x 18688 B
                                                           // total 125952 B

    const int t   = threadIdx.x;
    const int w   = t >> 6;
    const bool cw = (w < 4);          // compute waves 0..3, mem waves 4..7
    const int mt  = t & 255;
    const int nch = (B + SPB - 1) / SPB;
    const size_t limR = (size_t)B * 96;
    const size_t limP = (size_t)B * 72;

    // ---- prologue: mem waves stage chunk c0 into buffer 0 ----
    const int c0 = blockIdx.x;
    if (!cw && c0 < nch) {
        f32x4 vr[6], vp[5];
        load_regs(c0, mt, rot, pos, limR, limP, vr, vp);
        scatter_lds(mt, ldsR[0], ldsP[0], vr, vp);
    }
    __syncthreads();

    int i = 0, c = c0;
    for (; c < nch; c += GRIDP, ++i) {
        const int q = i & 1;
        if (cw) {
            // ---- compute chunk c from buffer q -> ldsO[q] ----
            const int l = t & 63;
            const int b = c * SPB + l;
            if (b < B) {
                const float* R = &ldsR[q][l * RPITCH];
                const float* P = &ldsP[q][l * PPITCH];
                float*       O = &ldsO[q][l * PPITCH];
                switch (w) {
                    case 0:  run_chain(MT0, PR0, 0, R, P, O); break;
                    case 1:  run_chain(MT1, PR1, 2, R, P, O); break;
                    case 2:  run_chain(MT2, PR2, 4, R, P, O); break;
                    default: run_chain(MT3, PR3, 4, R, P, O); break;
                }
            }
        } else {
            // ---- 1) issue next chunk's 11 global loads ----
            const int cn = c + GRIDP;
            const bool ldv = (cn < nch);
            f32x4 vr[6], vp[5];
            if (ldv) load_regs(cn, mt, rot, pos, limR, limP, vr, vp);
            // ---- 2) store chunk c-GRIDP from ldsO[q^1] (hides load lat) ----
            if (i > 0) store_chunk(ldsO[q^1], c - GRIDP, mt, limP, out);
            // ---- 3) scatter loads into buffers q^1 (disjoint from ldsO) ----
            if (ldv) scatter_lds(mt, ldsR[q^1], ldsP[q^1], vr, vp);
        }
        __syncthreads();
    }

    // ---- epilogue: store the final chunk's output ----
    if (!cw && i > 0)
        store_chunk(ldsO[(i-1) & 1], c - GRIDP, mt, limP, out);
}

extern "C" void kernel_launch(void* const* d_in, const int* in_sizes, int n_in,
                              void* d_out, int out_size, void* d_ws, size_t ws_size,
                              hipStream_t stream) {
    const int B = out_size / 72;           // (B,24,3)
    const void* rot = nullptr;
    const void* pos = nullptr;
    for (int i = 0; i < n_in; ++i) {       // resolve by size, not order
        if      (in_sizes[i] == B * 96) rot = d_in[i];
        else if (in_sizes[i] == B * 72) pos = d_in[i];
    }
    if (!rot) rot = d_in[2];
    if (!pos) pos = d_in[1];

    const int nch  = (B + SPB - 1) / SPB;  // 2048 chunks @ B=131072
    const int grid = (nch < GRIDP) ? nch : GRIDP;
    fk_kernel<<<grid, NTHR, 0, stream>>>(
        (const float*)rot, (const float*)pos, (float*)d_out, B);
}